// Round 7
// baseline (351.516 us; speedup 1.0000x reference)
//
#include <hip/hip_runtime.h>
#include <math.h>

#define F_DIM 64
#define K_CL 16
#define B_GR 16
#define SROW 72   // padded LDS row stride in f16 (144 B) -- used by k_fused only

typedef _Float16 h16;
using f16x4 = __attribute__((ext_vector_type(4))) _Float16;
using f16x8 = __attribute__((ext_vector_type(8))) _Float16;
using f32x4 = __attribute__((ext_vector_type(4))) float;
using fx2   = __attribute__((ext_vector_type(2))) float;
using fp16x2 = __attribute__((ext_vector_type(2))) __fp16;   // cvt_pkrtz return type

static __device__ inline unsigned h2u(fp16x2 h) {
    union { fp16x2 h; unsigned u; } x; x.h = h; return x.u;
}

// ---------------------------------------------------------------------------
// K1 (fused): same compute as round 6 (fp8 ssh). Output scheme changed:
//   - per-block PARTIAL stores (outxP[bid][1024], CCbP[bid][256]) -> no
//     atomics, no pre-zeroed buffers, memset dispatch eliminated.
//   - block 0 zeros oadj (k_edge's atomic target; k_edge runs strictly after
//     this kernel completes -> safe) and the election ticket.
// ---------------------------------------------------------------------------
__global__ __launch_bounds__(256) void k_fused(
    const float* __restrict__ x, const float* __restrict__ W, const float* __restrict__ bvec,
    uint4* __restrict__ ssh8, float* __restrict__ outxP, float* __restrict__ CCbP,
    float* __restrict__ oadj, unsigned* __restrict__ ticket)
{
    __shared__ float Wl[F_DIM * K_CL];
    __shared__ float bl[K_CL];
    __shared__ __align__(16) h16 stage[4][(16 + 16 + 64) * SROW];  // 55.3 KB

    int t = threadIdx.x;
    int bid = blockIdx.x;
    if (bid == 0) {
        // zero oadj (16*256 floats) + ticket; visible to k_edge via kernel boundary
#pragma unroll
        for (int i = 0; i < 16; ++i) oadj[t + i * 256] = 0.f;
        if (t == 0) *ticket = 0u;
    }
    for (int idx = t; idx < F_DIM * K_CL; idx += 256) Wl[idx] = W[idx];
    if (t < K_CL) bl[t] = bvec[t];
    __syncthreads();

    int wid = t >> 6, lane = t & 63;
    h16* Sg = stage[wid];            // sraw^T  [16][SROW]
    h16* Cg = Sg + 16 * SROW;        // ss^T    [16][SROW]
    h16* Xg = Cg + 16 * SROW;        // x^T     [64][SROW]

    size_t i = (size_t)bid * 256 + t;
    float s[16];
#pragma unroll
    for (int k = 0; k < 16; ++k) s[k] = bl[k];

    const float4* xp = reinterpret_cast<const float4*>(x + i * F_DIM);
#pragma unroll
    for (int j = 0; j < 16; ++j) {
        float4 q = xp[j];
        float xf[4] = {q.x, q.y, q.z, q.w};
#pragma unroll
        for (int ff = 0; ff < 4; ++ff) {
            int f = j * 4 + ff;
            float xv = xf[ff];
            Xg[f * SROW + lane] = (h16)xv;           // stage x^T
            const float4* wr = reinterpret_cast<const float4*>(&Wl[f * K_CL]);
            float4 w0 = wr[0], w1 = wr[1], w2 = wr[2], w3 = wr[3];
            s[0]  += xv * w0.x; s[1]  += xv * w0.y; s[2]  += xv * w0.z; s[3]  += xv * w0.w;
            s[4]  += xv * w1.x; s[5]  += xv * w1.y; s[6]  += xv * w1.z; s[7]  += xv * w1.w;
            s[8]  += xv * w2.x; s[9]  += xv * w2.y; s[10] += xv * w2.z; s[11] += xv * w2.w;
            s[12] += xv * w3.x; s[13] += xv * w3.y; s[14] += xv * w3.z; s[15] += xv * w3.w;
        }
    }

    // stage sraw^T
#pragma unroll
    for (int k = 0; k < 16; ++k) Sg[k * SROW + lane] = (h16)s[k];

    // softmax
    float m = s[0];
#pragma unroll
    for (int k = 1; k < 16; ++k) m = fmaxf(m, s[k]);
    float sum = 0.f;
#pragma unroll
    for (int k = 0; k < 16; ++k) { s[k] = __expf(s[k] - m); sum += s[k]; }
    float inv = 1.0f / sum;
#pragma unroll
    for (int k = 0; k < 16; ++k) s[k] *= inv;

    // stage ss^T (f16, for CC MFMA)
    f16x8 h0, h1;
#pragma unroll
    for (int k = 0; k < 8; ++k) { h0[k] = (h16)s[k]; h1[k] = (h16)s[k + 8]; }
#pragma unroll
    for (int k = 0; k < 8; ++k) {
        Cg[k * SROW + lane] = h0[k];
        Cg[(k + 8) * SROW + lane] = h1[k];
    }

    // global ssh write: fp8 e4m3, 16 B/node (one dwordx4)
    {
        unsigned d0, d1, d2, d3;
        d0 = __builtin_amdgcn_cvt_pk_fp8_f32(s[0],  s[1],  0,  false);
        d0 = __builtin_amdgcn_cvt_pk_fp8_f32(s[2],  s[3],  d0, true);
        d1 = __builtin_amdgcn_cvt_pk_fp8_f32(s[4],  s[5],  0,  false);
        d1 = __builtin_amdgcn_cvt_pk_fp8_f32(s[6],  s[7],  d1, true);
        d2 = __builtin_amdgcn_cvt_pk_fp8_f32(s[8],  s[9],  0,  false);
        d2 = __builtin_amdgcn_cvt_pk_fp8_f32(s[10], s[11], d2, true);
        d3 = __builtin_amdgcn_cvt_pk_fp8_f32(s[12], s[13], 0,  false);
        d3 = __builtin_amdgcn_cvt_pk_fp8_f32(s[14], s[15], d3, true);
        uint4 pk; pk.x = d0; pk.y = d1; pk.z = d2; pk.w = d3;
        ssh8[i] = pk;
    }

    // MFMA phase (wave-private LDS, no barrier needed)
    int q4 = lane >> 4, mm = lane & 15;
    f32x4 accO[4] = {{0.f,0.f,0.f,0.f},{0.f,0.f,0.f,0.f},{0.f,0.f,0.f,0.f},{0.f,0.f,0.f,0.f}};
    f32x4 accC = {0.f, 0.f, 0.f, 0.f};
#pragma unroll
    for (int h = 0; h < 2; ++h) {
        f16x8 aO = *(const f16x8*)&Sg[mm * SROW + h * 32 + q4 * 8];
        f16x8 aC = *(const f16x8*)&Cg[mm * SROW + h * 32 + q4 * 8];
        accC = __builtin_amdgcn_mfma_f32_16x16x32_f16(aC, aC, accC, 0, 0, 0);
#pragma unroll
        for (int ft = 0; ft < 4; ++ft) {
            f16x8 bO = *(const f16x8*)&Xg[(ft * 16 + mm) * SROW + h * 32 + q4 * 8];
            accO[ft] = __builtin_amdgcn_mfma_f32_16x16x32_f16(aO, bO, accO[ft], 0, 0, 0);
        }
    }
    __syncthreads();

    // block reduce (reuse staging LDS)
    float* redO = (float*)&stage[0][0];     // 4 x 1024
    float* redC = redO + 4096;              // 4 x 256
#pragma unroll
    for (int ft = 0; ft < 4; ++ft)
#pragma unroll
        for (int rg = 0; rg < 4; ++rg)
            redO[wid * 1024 + (q4 * 4 + rg) * 64 + ft * 16 + mm] = accO[ft][rg];
#pragma unroll
    for (int rg = 0; rg < 4; ++rg)
        redC[wid * 256 + (q4 * 4 + rg) * 16 + mm] = accC[rg];
    __syncthreads();

    // per-block PARTIAL stores (no atomics, no pre-zero)
#pragma unroll
    for (int it = 0; it < 4; ++it) {
        int idx = t + it * 256;
        float v = redO[idx] + redO[1024 + idx] + redO[2048 + idx] + redO[3072 + idx];
        outxP[(size_t)bid * 1024 + idx] = v;
    }
    {
        float v = redC[t] + redC[256 + t] + redC[512 + t] + redC[768 + t];
        CCbP[(size_t)bid * 256 + t] = v;
    }
}

// ---------------------------------------------------------------------------
// K2 v7: round-6-verified fp8 gather/tr-read/MFMA core, PLUS:
//   - chunks 0..31 per graph: reduce 32 outx partials for a 32-output slice,
//     apply selu, store to out directly (replaces k_final's selu grid).
//   - chunk 32 per graph: reduce CCb partials -> CCb (atomicExch, device scope).
//   - LAST block to finish (atomic ticket, __threadfence) runs the loss +
//     out_adj_norm tail; all cross-block data is read via device-scope
//     atomic reads (atomicAdd(p, 0.f)) to respect XCD non-coherence.
// k_final dispatch and the memset dispatch are gone: 2 dispatches total.
// ---------------------------------------------------------------------------
__global__ __launch_bounds__(256) void k_edge(
    const int* __restrict__ erow, const int* __restrict__ ecol, const float* __restrict__ ew,
    const uint4* __restrict__ ssh8, float* __restrict__ oadj,
    const float* __restrict__ outxP, const float* __restrict__ CCbP,
    float* __restrict__ CCb, float* __restrict__ out, unsigned* __restrict__ ticket,
    int edges_per_block, int edges_per_graph, int nmask, int npg, int nblocks)
{
    __shared__ float CCl[256];
    __shared__ __align__(16) h16 stageE[4][2048];   // per wave: A[64][16] + B[64][16] = 4 KB
    __shared__ float ddl[256];
    __shared__ float sp_s[B_GR], cl_s[B_GR], or_s[B_GR];
    __shared__ unsigned elect;

    int t = threadIdx.x;
    CCl[t] = 0.f;
    __syncthreads();

    int bid = blockIdx.x;
    int xcd = bid & 7;
    int slot = bid >> 3;
    int graph = xcd + 8 * (slot & 1);
    int chunk = slot >> 1;

    // ---- fused k_final work, part 1: partial reductions (independent) ----
    if (chunk < 32) {
        // reduce outx partials for outputs [chunk*32, chunk*32+32) of graph
        if (t < 32) {
            int idx = chunk * 32 + t;
            float sv = 0.f;
            for (int sub = 0; sub < 32; ++sub)
                sv += outxP[(size_t)(graph * 32 + sub) * 1024 + idx];
            float r = (sv > 0.f) ? (1.0507009873554805f * sv)
                                 : (1.0507009873554805f * 1.6732632423543772f * (__expf(sv) - 1.0f));
            out[graph * 1024 + idx] = r;
        }
    } else if (chunk == 32) {
        float sv = 0.f;
        for (int sub = 0; sub < 32; ++sub)
            sv += CCbP[(size_t)(graph * 32 + sub) * 256 + t];
        atomicExch(CCb + graph * 256 + t, sv);   // device-scope write
    }

    int wid = t >> 6, lane = t & 63;
    int q4 = lane >> 4, mm = lane & 15;
    h16* Ag = stageE[wid];

    int epw = edges_per_block >> 2;           // 512 edges per wave
    int nt  = epw >> 6;                       // 8 tiles of 64 edges
    size_t base = (size_t)graph * edges_per_graph
                + (size_t)chunk * edges_per_block
                + (size_t)wid * epw
                + lane;                       // 1 lane per edge

    f32x4 acc = {0.f, 0.f, 0.f, 0.f};

    // LDS image: A rows [64 edges][16 f16] at 32 B stride; B rows at +2048 B.
    f16x8* Aw = reinterpret_cast<f16x8*>(Ag);
    using lds_h16 = __attribute__((address_space(3))) h16;
    unsigned trA = (unsigned)(uintptr_t)(lds_h16*)Ag + (unsigned)(q4 * 256 + mm * 2);

    // decode one fp8 dword -> 4 f16 (2 packed dwords), scaled by w
    auto dec_dw = [](unsigned d, float w, unsigned& o0, unsigned& o1) {
        fx2 p = __builtin_amdgcn_cvt_pk_f32_fp8((int)d, false);
        fx2 q = __builtin_amdgcn_cvt_pk_f32_fp8((int)d, true);
        o0 = h2u(__builtin_amdgcn_cvt_pkrtz(p.x * w, p.y * w));
        o1 = h2u(__builtin_amdgcn_cvt_pkrtz(q.x * w, q.y * w));
    };

    auto compute_tile = [&](uint4 va, uint4 vb, float wv) {
        union { unsigned u[4]; f16x8 v; } alo, ahi, blo, bhi;
        dec_dw(va.x, wv, alo.u[0], alo.u[1]);
        dec_dw(va.y, wv, alo.u[2], alo.u[3]);
        dec_dw(va.z, wv, ahi.u[0], ahi.u[1]);
        dec_dw(va.w, wv, ahi.u[2], ahi.u[3]);
        dec_dw(vb.x, 1.0f, blo.u[0], blo.u[1]);
        dec_dw(vb.y, 1.0f, blo.u[2], blo.u[3]);
        dec_dw(vb.z, 1.0f, bhi.u[0], bhi.u[1]);
        dec_dw(vb.w, 1.0f, bhi.u[2], bhi.u[3]);

        Aw[lane * 2]           = alo.v;
        Aw[lane * 2 + 1]       = ahi.v;
        Aw[128 + lane * 2]     = blo.v;
        Aw[128 + lane * 2 + 1] = bhi.v;

        f16x4 xa0, xa1, xa2, xa3, xb0, xb1, xb2, xb3;
        asm volatile(
            "ds_read_b64_tr_b16 %0, %8\n\t"
            "ds_read_b64_tr_b16 %1, %8 offset:128\n\t"
            "ds_read_b64_tr_b16 %2, %8 offset:2048\n\t"
            "ds_read_b64_tr_b16 %3, %8 offset:2176\n\t"
            "ds_read_b64_tr_b16 %4, %8 offset:1024\n\t"
            "ds_read_b64_tr_b16 %5, %8 offset:1152\n\t"
            "ds_read_b64_tr_b16 %6, %8 offset:3072\n\t"
            "ds_read_b64_tr_b16 %7, %8 offset:3200\n\t"
            "s_waitcnt lgkmcnt(0)"
            : "=&v"(xa0), "=&v"(xa1), "=&v"(xb0), "=&v"(xb1),
              "=&v"(xa2), "=&v"(xa3), "=&v"(xb2), "=&v"(xb3)
            : "v"(trA)
            : "memory");
        __builtin_amdgcn_sched_barrier(0);

        f16x8 afL = __builtin_shufflevector(xa0, xa1, 0, 1, 2, 3, 4, 5, 6, 7);
        f16x8 bfL = __builtin_shufflevector(xb0, xb1, 0, 1, 2, 3, 4, 5, 6, 7);
        f16x8 afH = __builtin_shufflevector(xa2, xa3, 0, 1, 2, 3, 4, 5, 6, 7);
        f16x8 bfH = __builtin_shufflevector(xb2, xb3, 0, 1, 2, 3, 4, 5, 6, 7);
        acc = __builtin_amdgcn_mfma_f32_16x16x32_f16(afL, bfL, acc, 0, 0, 0);
        acc = __builtin_amdgcn_mfma_f32_16x16x32_f16(afH, bfH, acc, 0, 0, 0);
    };

    // ---- pipeline prologue ----
    int rC, cC; float wC;
    rC = erow[base]; cC = ecol[base]; wC = ew[base];
    uint4 ca = ssh8[(size_t)(rC & nmask)];
    uint4 cb = ssh8[(size_t)(cC & nmask)];
    int rN = 0, cN = 0; float wN = 0.f;
    {
        size_t e = base + 64;
        rN = erow[e]; cN = ecol[e]; wN = ew[e];
    }

    // ---- steady state ----
    for (int tt = 0; tt < nt - 1; ++tt) {
        uint4 na = ssh8[(size_t)(rN & nmask)];
        uint4 nb = ssh8[(size_t)(cN & nmask)];
        int t2 = (tt + 2 < nt) ? (tt + 2) : 0;
        size_t e2 = base + (size_t)t2 * 64;
        int r2 = erow[e2], c2 = ecol[e2];
        float w2 = ew[e2];

        compute_tile(ca, cb, wC);

        ca = na; cb = nb; wC = wN;
        rN = r2; cN = c2; wN = w2;
    }
    compute_tile(ca, cb, wC);

    // reduce: acc[rg] is oadj[row = q4*4+rg][col = mm] contribution
#pragma unroll
    for (int rg = 0; rg < 4; ++rg)
        atomicAdd(&CCl[(q4 * 4 + rg) * 16 + mm], acc[rg]);
    __syncthreads();
    atomicAdd(oadj + graph * 256 + t, CCl[t]);

    // ---- election: last block to finish runs the loss/norm tail ----
    __threadfence();
    __syncthreads();
    if (t == 0) elect = atomicAdd(ticket, 1u);
    __syncthreads();
    if (elect != (unsigned)(nblocks - 1)) return;

    // ===== fused k_final, part 2 (single block; device-scope atomic reads) ====
    {
        int b = t >> 4, k = t & 15;
        float* oabase = oadj + b * 256;
        float* ccbase = CCb + b * 256;

        float oar[16], ocol[16], ccr[16];
#pragma unroll
        for (int l = 0; l < 16; ++l) {
            oar[l]  = atomicAdd(&oabase[k * 16 + l], 0.f);
            ocol[l] = atomicAdd(&oabase[l * 16 + k], 0.f);
            ccr[l]  = atomicAdd(&ccbase[k * 16 + l], 0.f);
        }

        float rowsum_off = 0.f, trace_c = 0.f, rowsum_all = 0.f, fro2 = 0.f;
        float colsum = 0.f, csv = 0.f;
#pragma unroll
        for (int l = 0; l < 16; ++l) {
            float v = oar[l];
            rowsum_all += v;
            if (l == k) trace_c = v; else rowsum_off += v;
            float c = ccr[l];
            fro2 += c * c;
            csv += c;
            colsum += ocol[l];
        }
        float dd = sqrtf(rowsum_off) + 1e-12f;
        ddl[t] = dd;

        float ds2 = colsum * colsum, cs2 = csv * csv;
        float tr = trace_c, m2 = rowsum_all;
#pragma unroll
        for (int msk = 8; msk >= 1; msk >>= 1) {
            tr   += __shfl_xor(tr,   msk, 16);
            ds2  += __shfl_xor(ds2,  msk, 16);
            cs2  += __shfl_xor(cs2,  msk, 16);
            fro2 += __shfl_xor(fro2, msk, 16);
            m2   += __shfl_xor(m2,   msk, 16);
        }
        float invfro = 1.0f / sqrtf(fro2);
        float osum = 0.f;
#pragma unroll
        for (int l = 0; l < 16; ++l) {
            float v = ccr[l] * invfro - ((l == k) ? 0.25f : 0.f);
            osum += v * v;
        }
#pragma unroll
        for (int msk = 8; msk >= 1; msk >>= 1) osum += __shfl_xor(osum, msk, 16);

        if (k == 0) {
            sp_s[b] = tr / m2 - ds2 / (m2 * m2);
            cl_s[b] = sqrtf(cs2) / (float)npg * 4.0f - 1.0f;
            or_s[b] = sqrtf(osum);
        }
        __syncthreads();
        if (t == 0) {
            float a = 0.f, c = 0.f, o = 0.f;
            for (int i2 = 0; i2 < B_GR; ++i2) { a += sp_s[i2]; c += cl_s[i2]; o += or_s[i2]; }
            out[20480] = -a / 16.f;
            out[20481] = c / 16.f;
            out[20482] = o / 16.f;
        }

#pragma unroll
        for (int l = 0; l < 16; ++l) {
            float v = (l == k) ? 0.f : oar[l] / (dd * ddl[b * 16 + l]);
            out[16384 + b * 256 + k * 16 + l] = v;
        }
    }
}

// ---------------------------------------------------------------------------
extern "C" void kernel_launch(void* const* d_in, const int* in_sizes, int n_in,
                              void* d_out, int out_size, void* d_ws, size_t ws_size,
                              hipStream_t stream)
{
    const float* x    = (const float*)d_in[0];
    const float* W    = (const float*)d_in[1];
    const float* bvec = (const float*)d_in[2];
    const float* ew   = (const float*)d_in[3];
    const int* erow   = (const int*)d_in[4];
    const int* ecol   = (const int*)d_in[5];

    int Ntot = in_sizes[0] / F_DIM;           // 131072
    size_t E = (size_t)in_sizes[3];           // 4194304
    int npg  = Ntot / B_GR;                   // 8192
    int edges_per_graph = (int)(E / B_GR);    // 262144
    int nmask = Ntot - 1;
    int nfb   = Ntot / 256;                   // 512 k_fused blocks

    const int ADJ_BLOCKS = 2048;              // 128 per graph, 8 per CU
    int edges_per_block = (int)(E / ADJ_BLOCKS);          // 2048

    char* ws = (char*)d_ws;
    size_t o = 0;
    uint4* ssh8  = (uint4*)(ws + o);    o += (size_t)Ntot * 16;        // fp8 rows
    float* outxP = (float*)(ws + o);    o += (size_t)nfb * 1024 * 4;   // 2 MB partials
    float* CCbP  = (float*)(ws + o);    o += (size_t)nfb * 256 * 4;    // 0.5 MB partials
    float* oadj  = (float*)(ws + o);    o += (size_t)B_GR * 256 * 4;
    float* CCb   = (float*)(ws + o);    o += (size_t)B_GR * 256 * 4;
    unsigned* ticket = (unsigned*)(ws + o); o += 64;

    k_fused<<<nfb, 256, 0, stream>>>(x, W, bvec, ssh8, outxP, CCbP, oadj, ticket);
    k_edge<<<ADJ_BLOCKS, 256, 0, stream>>>(erow, ecol, ew, ssh8, oadj,
                                           outxP, CCbP, CCb, (float*)d_out, ticket,
                                           edges_per_block, edges_per_graph, nmask,
                                           npg, ADJ_BLOCKS);
}

// Round 8
// 175.638 us; speedup vs baseline: 2.0014x; 2.0014x over previous
//
#include <hip/hip_runtime.h>
#include <math.h>

#define F_DIM 64
#define K_CL 16
#define B_GR 16
#define SROW 72   // padded LDS row stride in f16 (144 B) -- used by k_fused only

typedef _Float16 h16;
using f16x4 = __attribute__((ext_vector_type(4))) _Float16;
using f16x8 = __attribute__((ext_vector_type(8))) _Float16;
using f32x4 = __attribute__((ext_vector_type(4))) float;
using fx2   = __attribute__((ext_vector_type(2))) float;
using fp16x2 = __attribute__((ext_vector_type(2))) __fp16;   // cvt_pkrtz return type

static __device__ inline unsigned h2u(fp16x2 h) {
    union { fp16x2 h; unsigned u; } x; x.h = h; return x.u;
}

// ---------------------------------------------------------------------------
// K1 (fused): round-6 compute (fp8 ssh). Outputs are per-block PARTIAL
// stores (outxP[bid][1024], CCbP[bid][256]) -> no atomics, no pre-zeroed
// buffers, memset dispatch eliminated. Block 0 zeros oadj (k_edge's atomic
// target; k_edge runs strictly after this kernel -> safe, verified r7).
// ---------------------------------------------------------------------------
__global__ __launch_bounds__(256) void k_fused(
    const float* __restrict__ x, const float* __restrict__ W, const float* __restrict__ bvec,
    uint4* __restrict__ ssh8, float* __restrict__ outxP, float* __restrict__ CCbP,
    float* __restrict__ oadj)
{
    __shared__ float Wl[F_DIM * K_CL];
    __shared__ float bl[K_CL];
    __shared__ __align__(16) h16 stage[4][(16 + 16 + 64) * SROW];  // 55.3 KB

    int t = threadIdx.x;
    int bid = blockIdx.x;
    if (bid == 0) {
#pragma unroll
        for (int i = 0; i < 16; ++i) oadj[t + i * 256] = 0.f;
    }
    for (int idx = t; idx < F_DIM * K_CL; idx += 256) Wl[idx] = W[idx];
    if (t < K_CL) bl[t] = bvec[t];
    __syncthreads();

    int wid = t >> 6, lane = t & 63;
    h16* Sg = stage[wid];            // sraw^T  [16][SROW]
    h16* Cg = Sg + 16 * SROW;        // ss^T    [16][SROW]
    h16* Xg = Cg + 16 * SROW;        // x^T     [64][SROW]

    size_t i = (size_t)bid * 256 + t;
    float s[16];
#pragma unroll
    for (int k = 0; k < 16; ++k) s[k] = bl[k];

    const float4* xp = reinterpret_cast<const float4*>(x + i * F_DIM);
#pragma unroll
    for (int j = 0; j < 16; ++j) {
        float4 q = xp[j];
        float xf[4] = {q.x, q.y, q.z, q.w};
#pragma unroll
        for (int ff = 0; ff < 4; ++ff) {
            int f = j * 4 + ff;
            float xv = xf[ff];
            Xg[f * SROW + lane] = (h16)xv;           // stage x^T
            const float4* wr = reinterpret_cast<const float4*>(&Wl[f * K_CL]);
            float4 w0 = wr[0], w1 = wr[1], w2 = wr[2], w3 = wr[3];
            s[0]  += xv * w0.x; s[1]  += xv * w0.y; s[2]  += xv * w0.z; s[3]  += xv * w0.w;
            s[4]  += xv * w1.x; s[5]  += xv * w1.y; s[6]  += xv * w1.z; s[7]  += xv * w1.w;
            s[8]  += xv * w2.x; s[9]  += xv * w2.y; s[10] += xv * w2.z; s[11] += xv * w2.w;
            s[12] += xv * w3.x; s[13] += xv * w3.y; s[14] += xv * w3.z; s[15] += xv * w3.w;
        }
    }

    // stage sraw^T
#pragma unroll
    for (int k = 0; k < 16; ++k) Sg[k * SROW + lane] = (h16)s[k];

    // softmax
    float m = s[0];
#pragma unroll
    for (int k = 1; k < 16; ++k) m = fmaxf(m, s[k]);
    float sum = 0.f;
#pragma unroll
    for (int k = 0; k < 16; ++k) { s[k] = __expf(s[k] - m); sum += s[k]; }
    float inv = 1.0f / sum;
#pragma unroll
    for (int k = 0; k < 16; ++k) s[k] *= inv;

    // stage ss^T (f16, for CC MFMA)
    f16x8 h0, h1;
#pragma unroll
    for (int k = 0; k < 8; ++k) { h0[k] = (h16)s[k]; h1[k] = (h16)s[k + 8]; }
#pragma unroll
    for (int k = 0; k < 8; ++k) {
        Cg[k * SROW + lane] = h0[k];
        Cg[(k + 8) * SROW + lane] = h1[k];
    }

    // global ssh write: fp8 e4m3, 16 B/node (one dwordx4)
    {
        unsigned d0, d1, d2, d3;
        d0 = __builtin_amdgcn_cvt_pk_fp8_f32(s[0],  s[1],  0,  false);
        d0 = __builtin_amdgcn_cvt_pk_fp8_f32(s[2],  s[3],  d0, true);
        d1 = __builtin_amdgcn_cvt_pk_fp8_f32(s[4],  s[5],  0,  false);
        d1 = __builtin_amdgcn_cvt_pk_fp8_f32(s[6],  s[7],  d1, true);
        d2 = __builtin_amdgcn_cvt_pk_fp8_f32(s[8],  s[9],  0,  false);
        d2 = __builtin_amdgcn_cvt_pk_fp8_f32(s[10], s[11], d2, true);
        d3 = __builtin_amdgcn_cvt_pk_fp8_f32(s[12], s[13], 0,  false);
        d3 = __builtin_amdgcn_cvt_pk_fp8_f32(s[14], s[15], d3, true);
        uint4 pk; pk.x = d0; pk.y = d1; pk.z = d2; pk.w = d3;
        ssh8[i] = pk;
    }

    // MFMA phase (wave-private LDS, no barrier needed)
    int q4 = lane >> 4, mm = lane & 15;
    f32x4 accO[4] = {{0.f,0.f,0.f,0.f},{0.f,0.f,0.f,0.f},{0.f,0.f,0.f,0.f},{0.f,0.f,0.f,0.f}};
    f32x4 accC = {0.f, 0.f, 0.f, 0.f};
#pragma unroll
    for (int h = 0; h < 2; ++h) {
        f16x8 aO = *(const f16x8*)&Sg[mm * SROW + h * 32 + q4 * 8];
        f16x8 aC = *(const f16x8*)&Cg[mm * SROW + h * 32 + q4 * 8];
        accC = __builtin_amdgcn_mfma_f32_16x16x32_f16(aC, aC, accC, 0, 0, 0);
#pragma unroll
        for (int ft = 0; ft < 4; ++ft) {
            f16x8 bO = *(const f16x8*)&Xg[(ft * 16 + mm) * SROW + h * 32 + q4 * 8];
            accO[ft] = __builtin_amdgcn_mfma_f32_16x16x32_f16(aO, bO, accO[ft], 0, 0, 0);
        }
    }
    __syncthreads();

    // block reduce (reuse staging LDS)
    float* redO = (float*)&stage[0][0];     // 4 x 1024
    float* redC = redO + 4096;              // 4 x 256
#pragma unroll
    for (int ft = 0; ft < 4; ++ft)
#pragma unroll
        for (int rg = 0; rg < 4; ++rg)
            redO[wid * 1024 + (q4 * 4 + rg) * 64 + ft * 16 + mm] = accO[ft][rg];
#pragma unroll
    for (int rg = 0; rg < 4; ++rg)
        redC[wid * 256 + (q4 * 4 + rg) * 16 + mm] = accC[rg];
    __syncthreads();

    // per-block PARTIAL stores (no atomics, no pre-zero)
#pragma unroll
    for (int it = 0; it < 4; ++it) {
        int idx = t + it * 256;
        float v = redO[idx] + redO[1024 + idx] + redO[2048 + idx] + redO[3072 + idx];
        outxP[(size_t)bid * 1024 + idx] = v;
    }
    {
        float v = redC[t] + redC[256 + t] + redC[512 + t] + redC[768 + t];
        CCbP[(size_t)bid * 256 + t] = v;
    }
}

// ---------------------------------------------------------------------------
// K2: EXACT round-6 core (fp8 gathers, tr-read + MFMA, 2-ahead prefetch).
// No fences, no election, no fused tail -- round 7 proved per-block
// __threadfence at 2048 blocks costs ~225 us of L2 writeback serialization.
// ---------------------------------------------------------------------------
__global__ __launch_bounds__(256) void k_edge(
    const int* __restrict__ erow, const int* __restrict__ ecol, const float* __restrict__ ew,
    const uint4* __restrict__ ssh8, float* __restrict__ oadj,
    int edges_per_block, int edges_per_graph, int nmask)
{
    __shared__ float CCl[256];
    __shared__ __align__(16) h16 stageE[4][2048];   // per wave: A[64][16] + B[64][16] = 4 KB
    int t = threadIdx.x;
    CCl[t] = 0.f;
    __syncthreads();

    int bid = blockIdx.x;
    int xcd = bid & 7;
    int slot = bid >> 3;
    int graph = xcd + 8 * (slot & 1);
    int chunk = slot >> 1;

    int wid = t >> 6, lane = t & 63;
    int q4 = lane >> 4, mm = lane & 15;
    h16* Ag = stageE[wid];

    int epw = edges_per_block >> 2;           // 512 edges per wave
    int nt  = epw >> 6;                       // 8 tiles of 64 edges
    size_t base = (size_t)graph * edges_per_graph
                + (size_t)chunk * edges_per_block
                + (size_t)wid * epw
                + lane;                       // 1 lane per edge

    f32x4 acc = {0.f, 0.f, 0.f, 0.f};

    // LDS image: A rows [64 edges][16 f16] at 32 B stride; B rows at +2048 B.
    f16x8* Aw = reinterpret_cast<f16x8*>(Ag);
    using lds_h16 = __attribute__((address_space(3))) h16;
    unsigned trA = (unsigned)(uintptr_t)(lds_h16*)Ag + (unsigned)(q4 * 256 + mm * 2);

    // decode one fp8 dword -> 4 f16 (2 packed dwords), scaled by w
    auto dec_dw = [](unsigned d, float w, unsigned& o0, unsigned& o1) {
        fx2 p = __builtin_amdgcn_cvt_pk_f32_fp8((int)d, false);
        fx2 q = __builtin_amdgcn_cvt_pk_f32_fp8((int)d, true);
        o0 = h2u(__builtin_amdgcn_cvt_pkrtz(p.x * w, p.y * w));
        o1 = h2u(__builtin_amdgcn_cvt_pkrtz(q.x * w, q.y * w));
    };

    auto compute_tile = [&](uint4 va, uint4 vb, float wv) {
        union { unsigned u[4]; f16x8 v; } alo, ahi, blo, bhi;
        dec_dw(va.x, wv, alo.u[0], alo.u[1]);
        dec_dw(va.y, wv, alo.u[2], alo.u[3]);
        dec_dw(va.z, wv, ahi.u[0], ahi.u[1]);
        dec_dw(va.w, wv, ahi.u[2], ahi.u[3]);
        dec_dw(vb.x, 1.0f, blo.u[0], blo.u[1]);
        dec_dw(vb.y, 1.0f, blo.u[2], blo.u[3]);
        dec_dw(vb.z, 1.0f, bhi.u[0], bhi.u[1]);
        dec_dw(vb.w, 1.0f, bhi.u[2], bhi.u[3]);

        Aw[lane * 2]           = alo.v;
        Aw[lane * 2 + 1]       = ahi.v;
        Aw[128 + lane * 2]     = blo.v;
        Aw[128 + lane * 2 + 1] = bhi.v;

        f16x4 xa0, xa1, xa2, xa3, xb0, xb1, xb2, xb3;
        asm volatile(
            "ds_read_b64_tr_b16 %0, %8\n\t"
            "ds_read_b64_tr_b16 %1, %8 offset:128\n\t"
            "ds_read_b64_tr_b16 %2, %8 offset:2048\n\t"
            "ds_read_b64_tr_b16 %3, %8 offset:2176\n\t"
            "ds_read_b64_tr_b16 %4, %8 offset:1024\n\t"
            "ds_read_b64_tr_b16 %5, %8 offset:1152\n\t"
            "ds_read_b64_tr_b16 %6, %8 offset:3072\n\t"
            "ds_read_b64_tr_b16 %7, %8 offset:3200\n\t"
            "s_waitcnt lgkmcnt(0)"
            : "=&v"(xa0), "=&v"(xa1), "=&v"(xb0), "=&v"(xb1),
              "=&v"(xa2), "=&v"(xa3), "=&v"(xb2), "=&v"(xb3)
            : "v"(trA)
            : "memory");
        __builtin_amdgcn_sched_barrier(0);

        f16x8 afL = __builtin_shufflevector(xa0, xa1, 0, 1, 2, 3, 4, 5, 6, 7);
        f16x8 bfL = __builtin_shufflevector(xb0, xb1, 0, 1, 2, 3, 4, 5, 6, 7);
        f16x8 afH = __builtin_shufflevector(xa2, xa3, 0, 1, 2, 3, 4, 5, 6, 7);
        f16x8 bfH = __builtin_shufflevector(xb2, xb3, 0, 1, 2, 3, 4, 5, 6, 7);
        acc = __builtin_amdgcn_mfma_f32_16x16x32_f16(afL, bfL, acc, 0, 0, 0);
        acc = __builtin_amdgcn_mfma_f32_16x16x32_f16(afH, bfH, acc, 0, 0, 0);
    };

    // ---- pipeline prologue ----
    int rC, cC; float wC;
    rC = erow[base]; cC = ecol[base]; wC = ew[base];
    uint4 ca = ssh8[(size_t)(rC & nmask)];
    uint4 cb = ssh8[(size_t)(cC & nmask)];
    int rN = 0, cN = 0; float wN = 0.f;
    {
        size_t e = base + 64;
        rN = erow[e]; cN = ecol[e]; wN = ew[e];
    }

    // ---- steady state ----
    for (int tt = 0; tt < nt - 1; ++tt) {
        uint4 na = ssh8[(size_t)(rN & nmask)];
        uint4 nb = ssh8[(size_t)(cN & nmask)];
        int t2 = (tt + 2 < nt) ? (tt + 2) : 0;
        size_t e2 = base + (size_t)t2 * 64;
        int r2 = erow[e2], c2 = ecol[e2];
        float w2 = ew[e2];

        compute_tile(ca, cb, wC);

        ca = na; cb = nb; wC = wN;
        rN = r2; cN = c2; wN = w2;
    }
    compute_tile(ca, cb, wC);

    // reduce: acc[rg] is oadj[row = q4*4+rg][col = mm] contribution
#pragma unroll
    for (int rg = 0; rg < 4; ++rg)
        atomicAdd(&CCl[(q4 * 4 + rg) * 16 + mm], acc[rg]);
    __syncthreads();
    atomicAdd(oadj + graph * 256 + t, CCl[t]);
}

// ---------------------------------------------------------------------------
// K3: round-6 tail, extended to reduce the outxP/CCbP partials first
// (coalesced, L2-warm, ~2.5 MB total). Grid 64 as before.
// ---------------------------------------------------------------------------
__global__ __launch_bounds__(256) void k_final(
    const float* __restrict__ outxP, const float* __restrict__ oadj,
    const float* __restrict__ CCbP, float* __restrict__ out, int npg)
{
    int t = threadIdx.x;
    int gid = blockIdx.x * 256 + t;
    {
        int g = gid >> 10, idx = gid & 1023;
        const float* p = outxP + (size_t)(g * 32) * 1024 + idx;
        float sv = 0.f;
#pragma unroll
        for (int sub = 0; sub < 32; ++sub) sv += p[(size_t)sub * 1024];
        float r = (sv > 0.f) ? (1.0507009873554805f * sv)
                             : (1.0507009873554805f * 1.6732632423543772f * (__expf(sv) - 1.0f));
        out[gid] = r;
    }

    if (blockIdx.x != 0) return;

    // reduce CC partials into LDS: ccred[g][t] = sum_sub CCbP[(g*32+sub)*256+t]
    __shared__ float ccred[16 * 256];   // 16 KB
    for (int g = 0; g < 16; ++g) {
        const float* p = CCbP + (size_t)(g * 32) * 256 + t;
        float sv = 0.f;
#pragma unroll
        for (int sub = 0; sub < 32; ++sub) sv += p[(size_t)sub * 256];
        ccred[g * 256 + t] = sv;
    }
    __syncthreads();

    int b = t >> 4, k = t & 15;
    const float* oar = oadj + b * 256 + k * 16;
    const float* ccr = &ccred[b * 256 + k * 16];

    float rowsum_off = 0.f, trace_c = 0.f, rowsum_all = 0.f, fro2 = 0.f, colsum = 0.f;
    float csv = 0.f;
#pragma unroll
    for (int l = 0; l < 16; ++l) {
        float v = oar[l];
        rowsum_all += v;
        if (l == k) trace_c = v; else rowsum_off += v;
        float c = ccr[l];
        fro2 += c * c;
        csv += c;                              // cluster_size[k] = sum_l CC[k][l]
        colsum += oadj[b * 256 + l * 16 + k];
    }
    float dd = sqrtf(rowsum_off) + 1e-12f;
    __shared__ float ddl[B_GR * K_CL];
    ddl[t] = dd;

    float ds2 = colsum * colsum, cs2 = csv * csv;
    float tr = trace_c, m2 = rowsum_all;
#pragma unroll
    for (int msk = 8; msk >= 1; msk >>= 1) {
        tr   += __shfl_xor(tr,   msk, 16);
        ds2  += __shfl_xor(ds2,  msk, 16);
        cs2  += __shfl_xor(cs2,  msk, 16);
        fro2 += __shfl_xor(fro2, msk, 16);
        m2   += __shfl_xor(m2,   msk, 16);
    }
    float invfro = 1.0f / sqrtf(fro2);
    float osum = 0.f;
#pragma unroll
    for (int l = 0; l < 16; ++l) {
        float v = ccr[l] * invfro - ((l == k) ? 0.25f : 0.f);
        osum += v * v;
    }
#pragma unroll
    for (int msk = 8; msk >= 1; msk >>= 1) osum += __shfl_xor(osum, msk, 16);

    __shared__ float sp_s[B_GR], cl_s[B_GR], or_s[B_GR];
    if (k == 0) {
        sp_s[b] = tr / m2 - ds2 / (m2 * m2);
        cl_s[b] = sqrtf(cs2) / (float)npg * 4.0f - 1.0f;
        or_s[b] = sqrtf(osum);
    }
    __syncthreads();
    if (t == 0) {
        float a = 0.f, c = 0.f, o = 0.f;
        for (int i = 0; i < B_GR; ++i) { a += sp_s[i]; c += cl_s[i]; o += or_s[i]; }
        out[20480] = -a / 16.f;
        out[20481] = c / 16.f;
        out[20482] = o / 16.f;
    }

#pragma unroll
    for (int l = 0; l < 16; ++l) {
        float v = (l == k) ? 0.f : oar[l] / (dd * ddl[b * 16 + l]);
        out[16384 + b * 256 + k * 16 + l] = v;
    }
}

// ---------------------------------------------------------------------------
extern "C" void kernel_launch(void* const* d_in, const int* in_sizes, int n_in,
                              void* d_out, int out_size, void* d_ws, size_t ws_size,
                              hipStream_t stream)
{
    const float* x    = (const float*)d_in[0];
    const float* W    = (const float*)d_in[1];
    const float* bvec = (const float*)d_in[2];
    const float* ew   = (const float*)d_in[3];
    const int* erow   = (const int*)d_in[4];
    const int* ecol   = (const int*)d_in[5];

    int Ntot = in_sizes[0] / F_DIM;           // 131072
    size_t E = (size_t)in_sizes[3];           // 4194304
    int npg  = Ntot / B_GR;                   // 8192
    int edges_per_graph = (int)(E / B_GR);    // 262144
    int nmask = Ntot - 1;
    int nfb   = Ntot / 256;                   // 512 k_fused blocks

    const int ADJ_BLOCKS = 2048;              // 128 per graph, 8 per CU
    int edges_per_block = (int)(E / ADJ_BLOCKS);          // 2048

    char* ws = (char*)d_ws;
    size_t o = 0;
    uint4* ssh8  = (uint4*)(ws + o);    o += (size_t)Ntot * 16;        // fp8 rows
    float* outxP = (float*)(ws + o);    o += (size_t)nfb * 1024 * 4;   // 2 MB partials
    float* CCbP  = (float*)(ws + o);    o += (size_t)nfb * 256 * 4;    // 0.5 MB partials
    float* oadj  = (float*)(ws + o);    o += (size_t)B_GR * 256 * 4;

    k_fused<<<nfb, 256, 0, stream>>>(x, W, bvec, ssh8, outxP, CCbP, oadj);
    k_edge<<<ADJ_BLOCKS, 256, 0, stream>>>(erow, ecol, ew, ssh8, oadj,
                                           edges_per_block, edges_per_graph, nmask);
    k_final<<<64, 256, 0, stream>>>(outxP, oadj, CCbP, (float*)d_out, npg);
}

// Round 9
// 167.019 us; speedup vs baseline: 2.1046x; 1.0516x over previous
//
#include <hip/hip_runtime.h>
#include <math.h>

#define F_DIM 64
#define K_CL 16
#define B_GR 16
#define SROW 72   // padded LDS row stride in f16 (144 B) -- used by k_fused only

typedef _Float16 h16;
using f16x4 = __attribute__((ext_vector_type(4))) _Float16;
using f16x8 = __attribute__((ext_vector_type(8))) _Float16;
using f32x4 = __attribute__((ext_vector_type(4))) float;
using fx2   = __attribute__((ext_vector_type(2))) float;
using fp16x2 = __attribute__((ext_vector_type(2))) __fp16;   // cvt_pkrtz return type

static __device__ inline unsigned h2u(fp16x2 h) {
    union { fp16x2 h; unsigned u; } x; x.h = h; return x.u;
}

// ---------------------------------------------------------------------------
// K1 (fused): round-8 verified. fp8 ssh rows; per-block PARTIAL stores
// (outxP[bid][1024], CCbP[bid][256]); block 0 zeros oadj (k_edge's atomic
// target, visible across the kernel boundary).
// ---------------------------------------------------------------------------
__global__ __launch_bounds__(256) void k_fused(
    const float* __restrict__ x, const float* __restrict__ W, const float* __restrict__ bvec,
    uint4* __restrict__ ssh8, float* __restrict__ outxP, float* __restrict__ CCbP,
    float* __restrict__ oadj)
{
    __shared__ float Wl[F_DIM * K_CL];
    __shared__ float bl[K_CL];
    __shared__ __align__(16) h16 stage[4][(16 + 16 + 64) * SROW];  // 55.3 KB

    int t = threadIdx.x;
    int bid = blockIdx.x;
    if (bid == 0) {
#pragma unroll
        for (int i = 0; i < 16; ++i) oadj[t + i * 256] = 0.f;
    }
    for (int idx = t; idx < F_DIM * K_CL; idx += 256) Wl[idx] = W[idx];
    if (t < K_CL) bl[t] = bvec[t];
    __syncthreads();

    int wid = t >> 6, lane = t & 63;
    h16* Sg = stage[wid];            // sraw^T  [16][SROW]
    h16* Cg = Sg + 16 * SROW;        // ss^T    [16][SROW]
    h16* Xg = Cg + 16 * SROW;        // x^T     [64][SROW]

    size_t i = (size_t)bid * 256 + t;
    float s[16];
#pragma unroll
    for (int k = 0; k < 16; ++k) s[k] = bl[k];

    const float4* xp = reinterpret_cast<const float4*>(x + i * F_DIM);
#pragma unroll
    for (int j = 0; j < 16; ++j) {
        float4 q = xp[j];
        float xf[4] = {q.x, q.y, q.z, q.w};
#pragma unroll
        for (int ff = 0; ff < 4; ++ff) {
            int f = j * 4 + ff;
            float xv = xf[ff];
            Xg[f * SROW + lane] = (h16)xv;           // stage x^T
            const float4* wr = reinterpret_cast<const float4*>(&Wl[f * K_CL]);
            float4 w0 = wr[0], w1 = wr[1], w2 = wr[2], w3 = wr[3];
            s[0]  += xv * w0.x; s[1]  += xv * w0.y; s[2]  += xv * w0.z; s[3]  += xv * w0.w;
            s[4]  += xv * w1.x; s[5]  += xv * w1.y; s[6]  += xv * w1.z; s[7]  += xv * w1.w;
            s[8]  += xv * w2.x; s[9]  += xv * w2.y; s[10] += xv * w2.z; s[11] += xv * w2.w;
            s[12] += xv * w3.x; s[13] += xv * w3.y; s[14] += xv * w3.z; s[15] += xv * w3.w;
        }
    }

    // stage sraw^T
#pragma unroll
    for (int k = 0; k < 16; ++k) Sg[k * SROW + lane] = (h16)s[k];

    // softmax
    float m = s[0];
#pragma unroll
    for (int k = 1; k < 16; ++k) m = fmaxf(m, s[k]);
    float sum = 0.f;
#pragma unroll
    for (int k = 0; k < 16; ++k) { s[k] = __expf(s[k] - m); sum += s[k]; }
    float inv = 1.0f / sum;
#pragma unroll
    for (int k = 0; k < 16; ++k) s[k] *= inv;

    // stage ss^T (f16, for CC MFMA)
    f16x8 h0, h1;
#pragma unroll
    for (int k = 0; k < 8; ++k) { h0[k] = (h16)s[k]; h1[k] = (h16)s[k + 8]; }
#pragma unroll
    for (int k = 0; k < 8; ++k) {
        Cg[k * SROW + lane] = h0[k];
        Cg[(k + 8) * SROW + lane] = h1[k];
    }

    // global ssh write: fp8 e4m3, 16 B/node (one dwordx4)
    {
        unsigned d0, d1, d2, d3;
        d0 = __builtin_amdgcn_cvt_pk_fp8_f32(s[0],  s[1],  0,  false);
        d0 = __builtin_amdgcn_cvt_pk_fp8_f32(s[2],  s[3],  d0, true);
        d1 = __builtin_amdgcn_cvt_pk_fp8_f32(s[4],  s[5],  0,  false);
        d1 = __builtin_amdgcn_cvt_pk_fp8_f32(s[6],  s[7],  d1, true);
        d2 = __builtin_amdgcn_cvt_pk_fp8_f32(s[8],  s[9],  0,  false);
        d2 = __builtin_amdgcn_cvt_pk_fp8_f32(s[10], s[11], d2, true);
        d3 = __builtin_amdgcn_cvt_pk_fp8_f32(s[12], s[13], 0,  false);
        d3 = __builtin_amdgcn_cvt_pk_fp8_f32(s[14], s[15], d3, true);
        uint4 pk; pk.x = d0; pk.y = d1; pk.z = d2; pk.w = d3;
        ssh8[i] = pk;
    }

    // MFMA phase (wave-private LDS, no barrier needed)
    int q4 = lane >> 4, mm = lane & 15;
    f32x4 accO[4] = {{0.f,0.f,0.f,0.f},{0.f,0.f,0.f,0.f},{0.f,0.f,0.f,0.f},{0.f,0.f,0.f,0.f}};
    f32x4 accC = {0.f, 0.f, 0.f, 0.f};
#pragma unroll
    for (int h = 0; h < 2; ++h) {
        f16x8 aO = *(const f16x8*)&Sg[mm * SROW + h * 32 + q4 * 8];
        f16x8 aC = *(const f16x8*)&Cg[mm * SROW + h * 32 + q4 * 8];
        accC = __builtin_amdgcn_mfma_f32_16x16x32_f16(aC, aC, accC, 0, 0, 0);
#pragma unroll
        for (int ft = 0; ft < 4; ++ft) {
            f16x8 bO = *(const f16x8*)&Xg[(ft * 16 + mm) * SROW + h * 32 + q4 * 8];
            accO[ft] = __builtin_amdgcn_mfma_f32_16x16x32_f16(aO, bO, accO[ft], 0, 0, 0);
        }
    }
    __syncthreads();

    // block reduce (reuse staging LDS)
    float* redO = (float*)&stage[0][0];     // 4 x 1024
    float* redC = redO + 4096;              // 4 x 256
#pragma unroll
    for (int ft = 0; ft < 4; ++ft)
#pragma unroll
        for (int rg = 0; rg < 4; ++rg)
            redO[wid * 1024 + (q4 * 4 + rg) * 64 + ft * 16 + mm] = accO[ft][rg];
#pragma unroll
    for (int rg = 0; rg < 4; ++rg)
        redC[wid * 256 + (q4 * 4 + rg) * 16 + mm] = accC[rg];
    __syncthreads();

    // per-block PARTIAL stores (no atomics, no pre-zero)
#pragma unroll
    for (int it = 0; it < 4; ++it) {
        int idx = t + it * 256;
        float v = redO[idx] + redO[1024 + idx] + redO[2048 + idx] + redO[3072 + idx];
        outxP[(size_t)bid * 1024 + idx] = v;
    }
    {
        float v = redC[t] + redC[256 + t] + redC[512 + t] + redC[768 + t];
        CCbP[(size_t)bid * 256 + t] = v;
    }
}

// ---------------------------------------------------------------------------
// K2: round-8 verified fp8 gather/tr-read/MFMA core, plus the r7-VERIFIED
// front-merge (no fences, no election): chunks 0..31 reduce outx partials +
// selu -> out; chunk 32 reduces CCb partials -> CCb (plain stores; the
// kernel boundary guarantees visibility to k_final). This work rides the
// gather-latency-bound main loop's idle VALU (12% busy).
// ---------------------------------------------------------------------------
__global__ __launch_bounds__(256) void k_edge(
    const int* __restrict__ erow, const int* __restrict__ ecol, const float* __restrict__ ew,
    const uint4* __restrict__ ssh8, float* __restrict__ oadj,
    const float* __restrict__ outxP, const float* __restrict__ CCbP,
    float* __restrict__ CCb, float* __restrict__ out,
    int edges_per_block, int edges_per_graph, int nmask)
{
    __shared__ float CCl[256];
    __shared__ __align__(16) h16 stageE[4][2048];   // per wave: A[64][16] + B[64][16] = 4 KB
    int t = threadIdx.x;
    CCl[t] = 0.f;
    __syncthreads();

    int bid = blockIdx.x;
    int xcd = bid & 7;
    int slot = bid >> 3;
    int graph = xcd + 8 * (slot & 1);
    int chunk = slot >> 1;

    // ---- fused k_final reductions (r7-verified; forward dataflow only) ----
    if (chunk < 32) {
        if (t < 32) {
            int idx = chunk * 32 + t;
            float sv = 0.f;
            for (int sub = 0; sub < 32; ++sub)
                sv += outxP[(size_t)(graph * 32 + sub) * 1024 + idx];
            float r = (sv > 0.f) ? (1.0507009873554805f * sv)
                                 : (1.0507009873554805f * 1.6732632423543772f * (__expf(sv) - 1.0f));
            out[graph * 1024 + idx] = r;
        }
    } else if (chunk == 32) {
        float sv = 0.f;
        for (int sub = 0; sub < 32; ++sub)
            sv += CCbP[(size_t)(graph * 32 + sub) * 256 + t];
        CCb[graph * 256 + t] = sv;      // plain store; kernel boundary publishes
    }

    int wid = t >> 6, lane = t & 63;
    int q4 = lane >> 4, mm = lane & 15;
    h16* Ag = stageE[wid];

    int epw = edges_per_block >> 2;           // 512 edges per wave
    int nt  = epw >> 6;                       // 8 tiles of 64 edges
    size_t base = (size_t)graph * edges_per_graph
                + (size_t)chunk * edges_per_block
                + (size_t)wid * epw
                + lane;                       // 1 lane per edge

    f32x4 acc = {0.f, 0.f, 0.f, 0.f};

    // LDS image: A rows [64 edges][16 f16] at 32 B stride; B rows at +2048 B.
    f16x8* Aw = reinterpret_cast<f16x8*>(Ag);
    using lds_h16 = __attribute__((address_space(3))) h16;
    unsigned trA = (unsigned)(uintptr_t)(lds_h16*)Ag + (unsigned)(q4 * 256 + mm * 2);

    // decode one fp8 dword -> 4 f16 (2 packed dwords), scaled by w
    auto dec_dw = [](unsigned d, float w, unsigned& o0, unsigned& o1) {
        fx2 p = __builtin_amdgcn_cvt_pk_f32_fp8((int)d, false);
        fx2 q = __builtin_amdgcn_cvt_pk_f32_fp8((int)d, true);
        o0 = h2u(__builtin_amdgcn_cvt_pkrtz(p.x * w, p.y * w));
        o1 = h2u(__builtin_amdgcn_cvt_pkrtz(q.x * w, q.y * w));
    };

    auto compute_tile = [&](uint4 va, uint4 vb, float wv) {
        union { unsigned u[4]; f16x8 v; } alo, ahi, blo, bhi;
        dec_dw(va.x, wv, alo.u[0], alo.u[1]);
        dec_dw(va.y, wv, alo.u[2], alo.u[3]);
        dec_dw(va.z, wv, ahi.u[0], ahi.u[1]);
        dec_dw(va.w, wv, ahi.u[2], ahi.u[3]);
        dec_dw(vb.x, 1.0f, blo.u[0], blo.u[1]);
        dec_dw(vb.y, 1.0f, blo.u[2], blo.u[3]);
        dec_dw(vb.z, 1.0f, bhi.u[0], bhi.u[1]);
        dec_dw(vb.w, 1.0f, bhi.u[2], bhi.u[3]);

        Aw[lane * 2]           = alo.v;
        Aw[lane * 2 + 1]       = ahi.v;
        Aw[128 + lane * 2]     = blo.v;
        Aw[128 + lane * 2 + 1] = bhi.v;

        f16x4 xa0, xa1, xa2, xa3, xb0, xb1, xb2, xb3;
        asm volatile(
            "ds_read_b64_tr_b16 %0, %8\n\t"
            "ds_read_b64_tr_b16 %1, %8 offset:128\n\t"
            "ds_read_b64_tr_b16 %2, %8 offset:2048\n\t"
            "ds_read_b64_tr_b16 %3, %8 offset:2176\n\t"
            "ds_read_b64_tr_b16 %4, %8 offset:1024\n\t"
            "ds_read_b64_tr_b16 %5, %8 offset:1152\n\t"
            "ds_read_b64_tr_b16 %6, %8 offset:3072\n\t"
            "ds_read_b64_tr_b16 %7, %8 offset:3200\n\t"
            "s_waitcnt lgkmcnt(0)"
            : "=&v"(xa0), "=&v"(xa1), "=&v"(xb0), "=&v"(xb1),
              "=&v"(xa2), "=&v"(xa3), "=&v"(xb2), "=&v"(xb3)
            : "v"(trA)
            : "memory");
        __builtin_amdgcn_sched_barrier(0);

        f16x8 afL = __builtin_shufflevector(xa0, xa1, 0, 1, 2, 3, 4, 5, 6, 7);
        f16x8 bfL = __builtin_shufflevector(xb0, xb1, 0, 1, 2, 3, 4, 5, 6, 7);
        f16x8 afH = __builtin_shufflevector(xa2, xa3, 0, 1, 2, 3, 4, 5, 6, 7);
        f16x8 bfH = __builtin_shufflevector(xb2, xb3, 0, 1, 2, 3, 4, 5, 6, 7);
        acc = __builtin_amdgcn_mfma_f32_16x16x32_f16(afL, bfL, acc, 0, 0, 0);
        acc = __builtin_amdgcn_mfma_f32_16x16x32_f16(afH, bfH, acc, 0, 0, 0);
    };

    // ---- pipeline prologue ----
    int rC, cC; float wC;
    rC = erow[base]; cC = ecol[base]; wC = ew[base];
    uint4 ca = ssh8[(size_t)(rC & nmask)];
    uint4 cb = ssh8[(size_t)(cC & nmask)];
    int rN = 0, cN = 0; float wN = 0.f;
    {
        size_t e = base + 64;
        rN = erow[e]; cN = ecol[e]; wN = ew[e];
    }

    // ---- steady state ----
    for (int tt = 0; tt < nt - 1; ++tt) {
        uint4 na = ssh8[(size_t)(rN & nmask)];
        uint4 nb = ssh8[(size_t)(cN & nmask)];
        int t2 = (tt + 2 < nt) ? (tt + 2) : 0;
        size_t e2 = base + (size_t)t2 * 64;
        int r2 = erow[e2], c2 = ecol[e2];
        float w2 = ew[e2];

        compute_tile(ca, cb, wC);

        ca = na; cb = nb; wC = wN;
        rN = r2; cN = c2; wN = w2;
    }
    compute_tile(ca, cb, wC);

    // reduce: acc[rg] is oadj[row = q4*4+rg][col = mm] contribution
#pragma unroll
    for (int rg = 0; rg < 4; ++rg)
        atomicAdd(&CCl[(q4 * 4 + rg) * 16 + mm], acc[rg]);
    __syncthreads();
    atomicAdd(oadj + graph * 256 + t, CCl[t]);
}

// ---------------------------------------------------------------------------
// K3: loss tail + out_adj_norm only (grid 1). oadj from k_edge atomics,
// CCb from k_edge chunk-32 stores -- both published by the kernel boundary.
// ---------------------------------------------------------------------------
__global__ __launch_bounds__(256) void k_final(
    const float* __restrict__ oadj, const float* __restrict__ CCb,
    float* __restrict__ out, int npg)
{
    int t = threadIdx.x;
    int b = t >> 4, k = t & 15;
    const float* oar = oadj + b * 256 + k * 16;
    const float* ccr = CCb + b * 256 + k * 16;

    float rowsum_off = 0.f, trace_c = 0.f, rowsum_all = 0.f, fro2 = 0.f, colsum = 0.f;
    float csv = 0.f;
#pragma unroll
    for (int l = 0; l < 16; ++l) {
        float v = oar[l];
        rowsum_all += v;
        if (l == k) trace_c = v; else rowsum_off += v;
        float c = ccr[l];
        fro2 += c * c;
        csv += c;                              // cluster_size[k] = sum_l CC[k][l]
        colsum += oadj[b * 256 + l * 16 + k];
    }
    float dd = sqrtf(rowsum_off) + 1e-12f;
    __shared__ float ddl[B_GR * K_CL];
    ddl[t] = dd;

    float ds2 = colsum * colsum, cs2 = csv * csv;
    float tr = trace_c, m2 = rowsum_all;
#pragma unroll
    for (int msk = 8; msk >= 1; msk >>= 1) {
        tr   += __shfl_xor(tr,   msk, 16);
        ds2  += __shfl_xor(ds2,  msk, 16);
        cs2  += __shfl_xor(cs2,  msk, 16);
        fro2 += __shfl_xor(fro2, msk, 16);
        m2   += __shfl_xor(m2,   msk, 16);
    }
    float invfro = 1.0f / sqrtf(fro2);
    float osum = 0.f;
#pragma unroll
    for (int l = 0; l < 16; ++l) {
        float v = ccr[l] * invfro - ((l == k) ? 0.25f : 0.f);
        osum += v * v;
    }
#pragma unroll
    for (int msk = 8; msk >= 1; msk >>= 1) osum += __shfl_xor(osum, msk, 16);

    __shared__ float sp_s[B_GR], cl_s[B_GR], or_s[B_GR];
    if (k == 0) {
        sp_s[b] = tr / m2 - ds2 / (m2 * m2);
        cl_s[b] = sqrtf(cs2) / (float)npg * 4.0f - 1.0f;
        or_s[b] = sqrtf(osum);
    }
    __syncthreads();
    if (t == 0) {
        float a = 0.f, c = 0.f, o = 0.f;
        for (int i = 0; i < B_GR; ++i) { a += sp_s[i]; c += cl_s[i]; o += or_s[i]; }
        out[20480] = -a / 16.f;
        out[20481] = c / 16.f;
        out[20482] = o / 16.f;
    }

#pragma unroll
    for (int l = 0; l < 16; ++l) {
        float v = (l == k) ? 0.f : oar[l] / (dd * ddl[b * 16 + l]);
        out[16384 + b * 256 + k * 16 + l] = v;
    }
}

// ---------------------------------------------------------------------------
extern "C" void kernel_launch(void* const* d_in, const int* in_sizes, int n_in,
                              void* d_out, int out_size, void* d_ws, size_t ws_size,
                              hipStream_t stream)
{
    const float* x    = (const float*)d_in[0];
    const float* W    = (const float*)d_in[1];
    const float* bvec = (const float*)d_in[2];
    const float* ew   = (const float*)d_in[3];
    const int* erow   = (const int*)d_in[4];
    const int* ecol   = (const int*)d_in[5];

    int Ntot = in_sizes[0] / F_DIM;           // 131072
    size_t E = (size_t)in_sizes[3];           // 4194304
    int npg  = Ntot / B_GR;                   // 8192
    int edges_per_graph = (int)(E / B_GR);    // 262144
    int nmask = Ntot - 1;
    int nfb   = Ntot / 256;                   // 512 k_fused blocks

    const int ADJ_BLOCKS = 2048;              // 128 per graph, 8 per CU
    int edges_per_block = (int)(E / ADJ_BLOCKS);          // 2048

    char* ws = (char*)d_ws;
    size_t o = 0;
    uint4* ssh8  = (uint4*)(ws + o);    o += (size_t)Ntot * 16;        // fp8 rows
    float* outxP = (float*)(ws + o);    o += (size_t)nfb * 1024 * 4;   // 2 MB partials
    float* CCbP  = (float*)(ws + o);    o += (size_t)nfb * 256 * 4;    // 0.5 MB partials
    float* oadj  = (float*)(ws + o);    o += (size_t)B_GR * 256 * 4;
    float* CCb   = (float*)(ws + o);    o += (size_t)B_GR * 256 * 4;

    k_fused<<<nfb, 256, 0, stream>>>(x, W, bvec, ssh8, outxP, CCbP, oadj);
    k_edge<<<ADJ_BLOCKS, 256, 0, stream>>>(erow, ecol, ew, ssh8, oadj,
                                           outxP, CCbP, CCb, (float*)d_out,
                                           edges_per_block, edges_per_graph, nmask);
    k_final<<<1, 256, 0, stream>>>(oadj, CCb, (float*)d_out, npg);
}